// Round 16
// baseline (407.456 us; speedup 1.0000x reference)
//
#include <hip/hip_runtime.h>

// B=131072 points (D=16 fp32), K=256 centers. Out (fp32): [B] argmin idx ++ [B,16] offsets.
//
// ROUND-16 = THREE-WAY AMPLIFIED MEASUREMENT. Session floor varies ~20us
// (r13: 36us direct; r1: ~56us), so total-dur deltas < ~8us are unfalsifiable.
// Fix: three variants, each REPEAT=8-amplified, launched sequentially in one
// call — rocprof reports each dispatch's dur_us separately. All compute the
// full identical output (idempotent; last write wins; absmax 0).
//   A kmeans_scalar: r14 scalar SGPR-fma loop, 2 pts/lane (38 VALU/iter)
//   B kmeans_pk2:    r15 LDS-fed v_pk_fma_f32, 2 pts/lane (24 VALU/iter)
//   C kmeans_pk4:    LDS-fed pk_fma, 4 pts/lane (~12 VALU/pt/iter, 2 blk/CU)
// Winner = min((dur-5)/8); round 17 ships it at REPEAT=1.
// score = c2[k] - 2*x.c per the expanded form; strict < + ascending k/chunk
// => lowest-k ties (jnp.argmin). r13 precedent: LLVM does not hoist the
// repeated pure scan (132us = 8x16.5).

constexpr int Bn = 131072;
constexpr int Kn = 256;
constexpr int Dn = 16;
constexpr int REPEAT = 8;

typedef float v2f __attribute__((ext_vector_type(2)));

// ---------------------------------------------------------------- A: scalar
__global__ __launch_bounds__(256, 8) void kmeans_scalar(
    const float* __restrict__ traj, const float* __restrict__ centers,
    float* __restrict__ out) {
  constexpr int PTS = 128, NW = 4, KC = Kn / NW;
  __shared__ float c2s[Kn];
  __shared__ float4 cs4[Kn][4];
  __shared__ float sbest[NW * PTS];
  __shared__ int sbi[NW * PTS];
  __shared__ int swin[PTS];

  const int t = threadIdx.x;
  const int blk = blockIdx.x;
  {
    const float4* cp = reinterpret_cast<const float4*>(centers + t * Dn);
    float4 a = cp[0], b = cp[1], c = cp[2], d = cp[3];
    float s = 0.0f;
    s = fmaf(a.x, a.x, s); s = fmaf(a.y, a.y, s); s = fmaf(a.z, a.z, s); s = fmaf(a.w, a.w, s);
    s = fmaf(b.x, b.x, s); s = fmaf(b.y, b.y, s); s = fmaf(b.z, b.z, s); s = fmaf(b.w, b.w, s);
    s = fmaf(c.x, c.x, s); s = fmaf(c.y, c.y, s); s = fmaf(c.z, c.z, s); s = fmaf(c.w, c.w, s);
    s = fmaf(d.x, d.x, s); s = fmaf(d.y, d.y, s); s = fmaf(d.z, d.z, s); s = fmaf(d.w, d.w, s);
    c2s[t] = s;
    cs4[t][0] = a; cs4[t][1] = b; cs4[t][2] = c; cs4[t][3] = d;
  }
  __syncthreads();

  const int w = __builtin_amdgcn_readfirstlane(t >> 6);
  const int l = t & 63;
  const int p0 = blk * PTS + l, p1 = p0 + 64;

  float y0[Dn], y1[Dn];
  {
    const float4* xa = reinterpret_cast<const float4*>(traj + (size_t)p0 * Dn);
    const float4* xb = reinterpret_cast<const float4*>(traj + (size_t)p1 * Dn);
#pragma unroll
    for (int q = 0; q < 4; ++q) {
      float4 a = xa[q], b = xb[q];
      y0[q*4+0] = -2.0f*a.x; y1[q*4+0] = -2.0f*b.x;
      y0[q*4+1] = -2.0f*a.y; y1[q*4+1] = -2.0f*b.y;
      y0[q*4+2] = -2.0f*a.z; y1[q*4+2] = -2.0f*b.z;
      y0[q*4+3] = -2.0f*a.w; y1[q*4+3] = -2.0f*b.w;
    }
  }

  float best0 = __builtin_inff(), best1 = __builtin_inff();
  int bi0 = 0, bi1 = 0;
  const int k0 = w * KC;
#pragma unroll 1
  for (int rep = 0; rep < REPEAT; ++rep) {
#pragma unroll 4
    for (int kk = 0; kk < KC; ++kk) {
      const int k = k0 + kk;
      const float* cr = centers + k * Dn;   // wave-uniform -> s_load
      const float c2k = c2s[k];
      float a0 = c2k, a1 = c2k;
#pragma unroll
      for (int d = 0; d < Dn; ++d) {
        const float c = cr[d];
        a0 = fmaf(y0[d], c, a0);
        a1 = fmaf(y1[d], c, a1);
      }
      if (a0 < best0) { best0 = a0; bi0 = k; }
      if (a1 < best1) { best1 = a1; bi1 = k; }
    }
  }
  sbest[w*PTS + l] = best0;      sbi[w*PTS + l] = bi0;
  sbest[w*PTS + 64 + l] = best1; sbi[w*PTS + 64 + l] = bi1;
  __syncthreads();

  if (t < PTS) {
    float b0 = sbest[t]; int i0 = sbi[t];
#pragma unroll
    for (int ww = 1; ww < NW; ++ww) {
      float b1 = sbest[ww*PTS + t]; int i1 = sbi[ww*PTS + t];
      if (b1 < b0) { b0 = b1; i0 = i1; }
    }
    swin[t] = i0;
    out[blk*PTS + t] = (float)i0;
  }
  __syncthreads();

#pragma unroll
  for (int it = 0; it < 2; ++it) {
    const int id = it*256 + t;
    const int pb = id >> 2, q = id & 3;
    const int pt = blk*PTS + pb;
    float4 xv = reinterpret_cast<const float4*>(traj + (size_t)pt * Dn)[q];
    float4 cv = cs4[swin[pb]][q];
    reinterpret_cast<float4*>(out + Bn)[(size_t)pt*4 + q] =
        make_float4(xv.x-cv.x, xv.y-cv.y, xv.z-cv.z, xv.w-cv.w);
  }
}

// ------------------------------------------------------- B: LDS-fed pk, 2pt
__global__ __launch_bounds__(256, 8) void kmeans_pk2(
    const float* __restrict__ traj, const float* __restrict__ centers,
    float* __restrict__ out) {
  constexpr int PTS = 128, NW = 4, KC = Kn / NW;
  __shared__ float c2s[Kn];
  __shared__ float4 cs4[Kn][4];
  __shared__ float sbest[NW * PTS];
  __shared__ int sbi[NW * PTS];
  __shared__ int swin[PTS];

  const int t = threadIdx.x;
  const int blk = blockIdx.x;
  {
    const float4* cp = reinterpret_cast<const float4*>(centers + t * Dn);
    float4 a = cp[0], b = cp[1], c = cp[2], d = cp[3];
    float s = 0.0f;
    s = fmaf(a.x, a.x, s); s = fmaf(a.y, a.y, s); s = fmaf(a.z, a.z, s); s = fmaf(a.w, a.w, s);
    s = fmaf(b.x, b.x, s); s = fmaf(b.y, b.y, s); s = fmaf(b.z, b.z, s); s = fmaf(b.w, b.w, s);
    s = fmaf(c.x, c.x, s); s = fmaf(c.y, c.y, s); s = fmaf(c.z, c.z, s); s = fmaf(c.w, c.w, s);
    s = fmaf(d.x, d.x, s); s = fmaf(d.y, d.y, s); s = fmaf(d.z, d.z, s); s = fmaf(d.w, d.w, s);
    c2s[t] = s;
    cs4[t][0] = a; cs4[t][1] = b; cs4[t][2] = c; cs4[t][3] = d;
  }
  __syncthreads();

  const int w = __builtin_amdgcn_readfirstlane(t >> 6);
  const int l = t & 63;
  const int p0 = blk * PTS + l, p1 = p0 + 64;

  v2f ya[8], yb[8];
  {
    const v2f* xa = reinterpret_cast<const v2f*>(traj + (size_t)p0 * Dn);
    const v2f* xb = reinterpret_cast<const v2f*>(traj + (size_t)p1 * Dn);
#pragma unroll
    for (int j = 0; j < 8; ++j) {
      v2f a = xa[j], b = xb[j];
      ya[j] = (v2f){-2.0f*a.x, -2.0f*a.y};
      yb[j] = (v2f){-2.0f*b.x, -2.0f*b.y};
    }
  }

  float best0 = __builtin_inff(), best1 = __builtin_inff();
  int bi0 = 0, bi1 = 0;
  const int k0 = w * KC;
#pragma unroll 1
  for (int rep = 0; rep < REPEAT; ++rep) {
#pragma unroll 4
    for (int kk = 0; kk < KC; ++kk) {
      const int k = k0 + kk;
      const v2f* rp = reinterpret_cast<const v2f*>(&cs4[k][0]);  // ds_read -> VGPR pairs
      const float c2k = c2s[k];
      v2f aa = (v2f){c2k, 0.0f}, ab = (v2f){c2k, 0.0f};
#pragma unroll
      for (int j = 0; j < 8; ++j) {
        const v2f c = rp[j];
        aa = ya[j] * c + aa;          // v_pk_fma_f32 all-VGPR
        ab = yb[j] * c + ab;
      }
      const float s0 = aa.x + aa.y, s1 = ab.x + ab.y;
      if (s0 < best0) { best0 = s0; bi0 = k; }
      if (s1 < best1) { best1 = s1; bi1 = k; }
    }
  }
  sbest[w*PTS + l] = best0;      sbi[w*PTS + l] = bi0;
  sbest[w*PTS + 64 + l] = best1; sbi[w*PTS + 64 + l] = bi1;
  __syncthreads();

  if (t < PTS) {
    float b0 = sbest[t]; int i0 = sbi[t];
#pragma unroll
    for (int ww = 1; ww < NW; ++ww) {
      float b1 = sbest[ww*PTS + t]; int i1 = sbi[ww*PTS + t];
      if (b1 < b0) { b0 = b1; i0 = i1; }
    }
    swin[t] = i0;
    out[blk*PTS + t] = (float)i0;
  }
  __syncthreads();

#pragma unroll
  for (int it = 0; it < 2; ++it) {
    const int id = it*256 + t;
    const int pb = id >> 2, q = id & 3;
    const int pt = blk*PTS + pb;
    float4 xv = reinterpret_cast<const float4*>(traj + (size_t)pt * Dn)[q];
    float4 cv = cs4[swin[pb]][q];
    reinterpret_cast<float4*>(out + Bn)[(size_t)pt*4 + q] =
        make_float4(xv.x-cv.x, xv.y-cv.y, xv.z-cv.z, xv.w-cv.w);
  }
}

// ------------------------------------------------------- C: LDS-fed pk, 4pt
__global__ __launch_bounds__(256, 2) void kmeans_pk4(
    const float* __restrict__ traj, const float* __restrict__ centers,
    float* __restrict__ out) {
  constexpr int PTS = 256, NW = 4, KC = Kn / NW;
  __shared__ float c2s[Kn];
  __shared__ float4 cs4[Kn][4];
  __shared__ float sbest[NW * PTS];
  __shared__ int sbi[NW * PTS];
  __shared__ int swin[PTS];

  const int t = threadIdx.x;
  const int blk = blockIdx.x;
  {
    const float4* cp = reinterpret_cast<const float4*>(centers + t * Dn);
    float4 a = cp[0], b = cp[1], c = cp[2], d = cp[3];
    float s = 0.0f;
    s = fmaf(a.x, a.x, s); s = fmaf(a.y, a.y, s); s = fmaf(a.z, a.z, s); s = fmaf(a.w, a.w, s);
    s = fmaf(b.x, b.x, s); s = fmaf(b.y, b.y, s); s = fmaf(b.z, b.z, s); s = fmaf(b.w, b.w, s);
    s = fmaf(c.x, c.x, s); s = fmaf(c.y, c.y, s); s = fmaf(c.z, c.z, s); s = fmaf(c.w, c.w, s);
    s = fmaf(d.x, d.x, s); s = fmaf(d.y, d.y, s); s = fmaf(d.z, d.z, s); s = fmaf(d.w, d.w, s);
    c2s[t] = s;
    cs4[t][0] = a; cs4[t][1] = b; cs4[t][2] = c; cs4[t][3] = d;
  }
  __syncthreads();

  const int w = __builtin_amdgcn_readfirstlane(t >> 6);
  const int l = t & 63;
  const int pbase = blk * PTS + l;   // pts: pbase + {0,64,128,192}

  v2f ya[8], yb[8], yc[8], yd[8];
  {
    const v2f* x0 = reinterpret_cast<const v2f*>(traj + (size_t)(pbase      ) * Dn);
    const v2f* x1 = reinterpret_cast<const v2f*>(traj + (size_t)(pbase +  64) * Dn);
    const v2f* x2 = reinterpret_cast<const v2f*>(traj + (size_t)(pbase + 128) * Dn);
    const v2f* x3 = reinterpret_cast<const v2f*>(traj + (size_t)(pbase + 192) * Dn);
#pragma unroll
    for (int j = 0; j < 8; ++j) {
      v2f a = x0[j], b = x1[j], c = x2[j], d = x3[j];
      ya[j] = (v2f){-2.0f*a.x, -2.0f*a.y};
      yb[j] = (v2f){-2.0f*b.x, -2.0f*b.y};
      yc[j] = (v2f){-2.0f*c.x, -2.0f*c.y};
      yd[j] = (v2f){-2.0f*d.x, -2.0f*d.y};
    }
  }

  float best0 = __builtin_inff(), best1 = __builtin_inff();
  float best2 = __builtin_inff(), best3 = __builtin_inff();
  int bi0 = 0, bi1 = 0, bi2 = 0, bi3 = 0;
  const int k0 = w * KC;
#pragma unroll 1
  for (int rep = 0; rep < REPEAT; ++rep) {
#pragma unroll 4
    for (int kk = 0; kk < KC; ++kk) {
      const int k = k0 + kk;
      const v2f* rp = reinterpret_cast<const v2f*>(&cs4[k][0]);
      const float c2k = c2s[k];
      v2f aa = (v2f){c2k, 0.0f}, ab = aa, ac = aa, ad = aa;
#pragma unroll
      for (int j = 0; j < 8; ++j) {
        const v2f c = rp[j];
        aa = ya[j] * c + aa;
        ab = yb[j] * c + ab;
        ac = yc[j] * c + ac;
        ad = yd[j] * c + ad;
      }
      const float s0 = aa.x + aa.y, s1 = ab.x + ab.y;
      const float s2 = ac.x + ac.y, s3 = ad.x + ad.y;
      if (s0 < best0) { best0 = s0; bi0 = k; }
      if (s1 < best1) { best1 = s1; bi1 = k; }
      if (s2 < best2) { best2 = s2; bi2 = k; }
      if (s3 < best3) { best3 = s3; bi3 = k; }
    }
  }
  sbest[w*PTS + l      ] = best0; sbi[w*PTS + l      ] = bi0;
  sbest[w*PTS + l +  64] = best1; sbi[w*PTS + l +  64] = bi1;
  sbest[w*PTS + l + 128] = best2; sbi[w*PTS + l + 128] = bi2;
  sbest[w*PTS + l + 192] = best3; sbi[w*PTS + l + 192] = bi3;
  __syncthreads();

  {
    float b0 = sbest[t]; int i0 = sbi[t];
#pragma unroll
    for (int ww = 1; ww < NW; ++ww) {
      float b1 = sbest[ww*PTS + t]; int i1 = sbi[ww*PTS + t];
      if (b1 < b0) { b0 = b1; i0 = i1; }
    }
    swin[t] = i0;
    out[blk*PTS + t] = (float)i0;
  }
  __syncthreads();

#pragma unroll
  for (int it = 0; it < 4; ++it) {
    const int id = it*256 + t;
    const int pb = id >> 2, q = id & 3;
    const int pt = blk*PTS + pb;
    float4 xv = reinterpret_cast<const float4*>(traj + (size_t)pt * Dn)[q];
    float4 cv = cs4[swin[pb]][q];
    reinterpret_cast<float4*>(out + Bn)[(size_t)pt*4 + q] =
        make_float4(xv.x-cv.x, xv.y-cv.y, xv.z-cv.z, xv.w-cv.w);
  }
}

extern "C" void kernel_launch(void* const* d_in, const int* in_sizes, int n_in,
                              void* d_out, int out_size, void* d_ws, size_t ws_size,
                              hipStream_t stream) {
  (void)in_sizes; (void)n_in; (void)out_size; (void)d_ws; (void)ws_size;
  const float* traj = (const float*)d_in[0];     // [131072, 16]
  const float* centers = (const float*)d_in[1];  // [256, 16]
  float* out = (float*)d_out;                    // [131072] idx ++ [131072*16] offsets
  // Three amplified variants, each writes the full (identical) output.
  kmeans_scalar<<<Bn / 128, 256, 0, stream>>>(traj, centers, out);
  kmeans_pk2   <<<Bn / 128, 256, 0, stream>>>(traj, centers, out);
  kmeans_pk4   <<<Bn / 256, 256, 0, stream>>>(traj, centers, out);
}